// Round 7
// baseline (477.699 us; speedup 1.0000x reference)
//
#include <hip/hip_runtime.h>

// ---------------------------------------------------------------------------
// MultiHeadAttention fused pipeline for MI355X (gfx950), fp16 MFMA path.
// B=2, S=2048, D=1024, H=16, Dh=64.
// d_out = [out (2*2048*1024 f32)] ++ [attn (2*16*2048*2048 f32)]
// Round 7: single-pass attention. Block = 16 full q-rows x all 2048 k.
// 8 waves x 256-col chunks: QK -> unnormalized exp2 -> P f16 in LDS +
// partial sums + partial PV; one barrier; linv; ctx via LDS atomicAdd;
// attn stored as 16 rows x 8 KB SEQUENTIAL nontemporal bursts (the R6
// counters showed the scattered 256B@8KB-stride store stream was the
// 2.45 TB/s limiter; sequential NT should approach fill-kernel BW).
// ---------------------------------------------------------------------------

using f16   = _Float16;
using f16x4 = __attribute__((ext_vector_type(4))) f16;
using f16x8 = __attribute__((ext_vector_type(8))) f16;
using f32x4 = __attribute__((ext_vector_type(4))) float;

#define MFMA16(a, b, c) __builtin_amdgcn_mfma_f32_16x16x32_f16((a), (b), (c), 0, 0, 0)

__device__ static inline float fexp2(float x) {
#if __has_builtin(__builtin_amdgcn_exp2f)
  return __builtin_amdgcn_exp2f(x);
#else
  return exp2f(x);
#endif
}

// (1/8) * log2(e): softmax scale folded into exp2 argument
#define C1 0.18033688011112042f

// async global->LDS, 16 bytes per lane; lptr must be wave-uniform.
__device__ static inline void gld16(const void* gptr, void* lptr) {
  __builtin_amdgcn_global_load_lds(
      (const __attribute__((address_space(1))) void*)gptr,
      (__attribute__((address_space(3))) void*)lptr, 16, 0, 0);
}

__device__ static inline unsigned int pack2(float a, float b) {
  union { f16 h[2]; unsigned int u; } x;
  x.h[0] = (f16)a; x.h[1] = (f16)b;
  return x.u;
}

// ---------------------------------------------------------------------------
// Kernel 0: cast all fp32 inputs to fp16 into workspace.
// ---------------------------------------------------------------------------
__global__ __launch_bounds__(256) void cast_all(
    const float* __restrict__ q, const float* __restrict__ k,
    const float* __restrict__ v, const float* __restrict__ wq,
    const float* __restrict__ wk, const float* __restrict__ wv,
    const float* __restrict__ wfc, f16* __restrict__ ws) {
  int i = blockIdx.x * 256 + threadIdx.x;  // vec4 index, 0..4194303
  const float* src;
  f16* dst;
  int li;
  if (i < 3145728) {
    if (i < 1048576)      { src = q; dst = ws;            li = i; }
    else if (i < 2097152) { src = k; dst = ws + 4194304;  li = i - 1048576; }
    else                  { src = v; dst = ws + 8388608;  li = i - 2097152; }
  } else {
    int j = i - 3145728;              // 0..1048575 over 4 weights
    int wsel = j >> 18;               // 262144 vec4 per weight
    src = (wsel == 0) ? wq : (wsel == 1) ? wk : (wsel == 2) ? wv : wfc;
    dst = ws + 12582912 + wsel * 1048576;
    li = j & 262143;
  }
  float4 x = ((const float4*)src)[li];
  f16x4 y;
  y[0] = (f16)x.x; y[1] = (f16)x.y; y[2] = (f16)x.z; y[3] = (f16)x.w;
  ((f16x4*)dst)[li] = y;
}

// ---------------------------------------------------------------------------
// GEMM: C = A[4096x1024] * W[1024x1024]^T   (both stored [row][k], fp16)
// 128 x BN tile, BK=64, 4 waves (2x2), 16x16x32 MFMA, XOR-swizzled LDS,
// global_load_lds(16B) staging with pre-swizzled global source.
// MODE 3 (BN=64): C[m][n] + bias -> out fp32 [M,N]   (grid 16 x 32)
// MODE 4 (BN=128): merged QKV. grid 24 x 32. wsel = nb3>>10 picks {q,k,v}
//   input and weight. wsel 0/1 -> qh/kh [B,H,S,Dh] f16; wsel 2 -> swapped
//   roles, vt [B,H,Dh,S] f16.
// ---------------------------------------------------------------------------
template <int MODE, int BN>
__global__ __launch_bounds__(256) void gemm_bt(
    const f16* __restrict__ A0, const f16* __restrict__ W0,
    const float* __restrict__ bias, void* __restrict__ Cout) {
  constexpr int FJ = BN / 32;          // B-frags per wave (BN=128->4, 64->2)
  __shared__ unsigned short XA[8192];  // 128 rows x 64 k x 2B = 16 KB
  __shared__ unsigned short WB[BN * 64];
  int tid = threadIdx.x;
  int w = tid >> 6, l = tid & 63, lq = l & 15, g = l >> 4;
  int nb3 = blockIdx.x * BN, mb = blockIdx.y * 128;
  int wsel = (MODE == 4) ? (nb3 >> 10) : 0;
  int nb = (MODE == 4) ? (nb3 & 1023) : nb3;
  const f16* A = (MODE == 4) ? A0 + (size_t)wsel * 4194304 : A0;
  const f16* W = (MODE == 4) ? W0 + (size_t)wsel * 1048576 : W0;
  bool swapR = (MODE == 4) && (wsel == 2);
  int wi = w >> 1, wj = w & 1;

  f32x4 acc[4][FJ];
#pragma unroll
  for (int i = 0; i < 4; i++)
#pragma unroll
    for (int j = 0; j < FJ; j++) acc[i][j] = (f32x4){0.f, 0.f, 0.f, 0.f};

  char* Xb = (char*)XA;
  char* Wb = (char*)WB;
  int row = tid >> 3;                    // 0..31
  int c = (tid & 7) ^ (row & 7);         // pre-swizzled global chunk
  const f16* Asrc = A + (size_t)(mb + row) * 1024 + c * 8;
  const f16* Wsrc = W + (size_t)(nb + row) * 1024 + c * 8;

  for (int k0 = 0; k0 < 1024; k0 += 64) {
#pragma unroll
    for (int i2 = 0; i2 < 4; i2++)
      gld16(Asrc + k0 + i2 * 32 * 1024, Xb + i2 * 4096 + w * 1024);
#pragma unroll
    for (int i2 = 0; i2 < BN / 32; i2++)
      gld16(Wsrc + k0 + i2 * 32 * 1024, Wb + i2 * 4096 + w * 1024);
    __syncthreads();

    const char* at = swapR ? Wb : Xb;
    const char* bt = swapR ? Xb : Wb;

    f16x8 bfr[FJ][2];
#pragma unroll
    for (int f = 0; f < FJ; f++) {
      int r = wj * (BN / 2) + f * 16 + lq;
      int sw = (r & 7) << 4;
      bfr[f][0] = *(const f16x8*)(bt + r * 128 + ((g * 16) ^ sw));
      bfr[f][1] = *(const f16x8*)(bt + r * 128 + ((64 + g * 16) ^ sw));
    }
#pragma unroll
    for (int fi = 0; fi < 4; fi++) {
      int r = wi * 64 + fi * 16 + lq;
      int sw = (r & 7) << 4;
      f16x8 a0 = *(const f16x8*)(at + r * 128 + ((g * 16) ^ sw));
      f16x8 a1 = *(const f16x8*)(at + r * 128 + ((64 + g * 16) ^ sw));
#pragma unroll
      for (int fj = 0; fj < FJ; fj++) {
        acc[fi][fj] = MFMA16(a0, bfr[fj][0], acc[fi][fj]);
        acc[fi][fj] = MFMA16(a1, bfr[fj][1], acc[fi][fj]);
      }
    }
    __syncthreads();
  }

  // epilogue: C frag element (row = g*4+jj, col = lq)
#pragma unroll
  for (int fi = 0; fi < 4; fi++) {
#pragma unroll
    for (int fj = 0; fj < FJ; fj++) {
#pragma unroll
      for (int jj = 0; jj < 4; jj++) {
        float v = acc[fi][fj][jj];
        int iG = (swapR ? nb : mb) + wi * 64 + fi * 16 + g * 4 + jj;
        int jG = (swapR ? mb : nb) + wj * (BN / 2) + fj * 16 + lq;
        if constexpr (MODE == 3) {
          int m2 = iG, n2 = jG;
          ((float*)Cout)[(size_t)m2 * 1024 + n2] = v + bias[n2];
        } else {
          f16* dstb = (f16*)Cout + (size_t)wsel * 4194304;
          if (!swapR) {
            int m2 = iG, n2 = jG;  // m = b*2048+s, n = h*64+dh
            size_t dst = (size_t)((m2 >> 11) * 16 + (n2 >> 6)) * 131072 +
                         (size_t)(m2 & 2047) * 64 + (n2 & 63);
            dstb[dst] = (f16)v;
          } else {
            int n2 = iG, m2 = jG;  // vt[(b*1024+n)*2048 + s]
            size_t dst = (size_t)((m2 >> 11) * 1024 + n2) * 2048 + (m2 & 2047);
            dstb[dst] = (f16)v;
          }
        }
      }
    }
  }
}

// ---------------------------------------------------------------------------
// Round-7 single-pass attention.
// grid 4096 (XCD-swizzled: 512/XCD = 4 bh x 128 row-tiles), 512 threads.
// Block owns 16 q-rows x all 2048 k. Wave w owns k-chunk [w*256, w*256+256).
// Phase 1 (per wave, no syncs): 4 tiles of 64 k:
//   QK swapped mfma(K,Q) from direct-global K frags (L2-resident via swizzle)
//   -> e = exp2(s*C1) UNNORMALIZED -> f16 into XOR-swizzled P[w][16][256]
//   -> ls partial row-sum; PV swapped mfma(Vt, P^T) -> partial ctx^T in regs.
// Barrier; linv = 1/sum (16 threads); barrier.
// Phase 2: ctx partials * linv atomicAdd into CT[16][64] (LDS, f32);
//   attn store: 32 threads/row, per-instr 2 rows x 512 B CONTIGUOUS
//   nontemporal float4 bursts (full rows written sequentially).
// Barrier; ctx f16 store.
// LDS = 64 KB P + 4 KB CT + 0.6 KB -> 2 blocks/CU (16 waves/CU).
// ---------------------------------------------------------------------------
__global__ __launch_bounds__(512, 4) void attn_one(
    const f16* __restrict__ qh, const f16* __restrict__ kh,
    const f16* __restrict__ vt, float* __restrict__ attn,
    f16* __restrict__ ctx) {
  __shared__ unsigned short Pl[8][4096];  // per-wave [16 q][256 k] f16, 64 KB
  __shared__ float CT[16][64];            // linv-scaled ctx^T accumulator
  __shared__ float LV[8][16];             // per-wave partial row sums
  __shared__ float LI[16];                // 1 / row sum
  int tid = threadIdx.x;
  int w = tid >> 6, l = tid & 63, lq = l & 15, g = l >> 4;

  // XCD swizzle: 512 blocks/XCD = 4 bh x 128 row-tiles (bijective)
  int bid = blockIdx.x;
  int xcd = bid & 7, j = bid >> 3;
  int bh = xcd * 4 + (j >> 7);
  int rt = j & 127;
  int rowbase = rt * 16;

  // zero CT
  if (tid < 256) {
    float* ctf = (float*)CT;
    ctf[tid] = 0.f; ctf[tid + 256] = 0.f; ctf[tid + 512] = 0.f;
    ctf[tid + 768] = 0.f;
  }

  const f16* qrow = qh + ((size_t)bh * 2048 + rowbase + lq) * 64;
  f16x8 qf0 = *(const f16x8*)(qrow + g * 8);
  f16x8 qf1 = *(const f16x8*)(qrow + 32 + g * 8);

  const f16* kbh = kh + (size_t)bh * 131072;
  const f16* vbh = vt + (size_t)bh * 131072;
  char* Pw = (char*)Pl[w];
  int swz = (lq & 7) << 4;
  int kc0 = w * 256;

  float ls = 0.f;
  f32x4 acc[4];
#pragma unroll
  for (int i = 0; i < 4; i++) acc[i] = (f32x4){0.f, 0.f, 0.f, 0.f};

  for (int t = 0; t < 4; t++) {
    int kt = kc0 + t * 64;
    int tl2 = t * 128;  // byte col base of this tile within the P row
#pragma unroll
    for (int cf = 0; cf < 4; cf++) {
      const f16* kr = kbh + (size_t)(kt + cf * 16 + lq) * 64 + g * 8;
      f16x8 ka  = *(const f16x8*)kr;
      f16x8 kb2 = *(const f16x8*)(kr + 32);
      f32x4 s = (f32x4){0.f, 0.f, 0.f, 0.f};
      s = MFMA16(ka, qf0, s);
      s = MFMA16(kb2, qf1, s);
      float e0 = fexp2(s[0] * C1);
      float e1 = fexp2(s[1] * C1);
      float e2 = fexp2(s[2] * C1);
      float e3 = fexp2(s[3] * C1);
      ls += (e0 + e1) + (e2 + e3);
      int k0b = tl2 + (cf * 16 + g * 4) * 2;  // byte col
      *(unsigned int*)(Pw + lq * 512 + (k0b ^ swz))       = pack2(e0, e1);
      *(unsigned int*)(Pw + lq * 512 + ((k0b + 4) ^ swz)) = pack2(e2, e3);
    }
    // PV (swapped): partial ctx^T[dh][q] += Vt * P^T
    f16x8 pb0 = *(const f16x8*)(Pw + lq * 512 + ((tl2 + g * 16) ^ swz));
    f16x8 pb1 = *(const f16x8*)(Pw + lq * 512 + ((tl2 + 64 + g * 16) ^ swz));
#pragma unroll
    for (int af = 0; af < 4; af++) {
      const f16* vr = vbh + (size_t)(af * 16 + lq) * 2048 + kt + g * 8;
      f16x8 va0 = *(const f16x8*)vr;
      f16x8 va1 = *(const f16x8*)(vr + 32);
      acc[af] = MFMA16(va0, pb0, acc[af]);
      acc[af] = MFMA16(va1, pb1, acc[af]);
    }
  }

  // partial row sums (this wave's 256-col chunk)
  ls += __shfl_xor(ls, 16);
  ls += __shfl_xor(ls, 32);
  if (l < 16) LV[w][l] = ls;
  __syncthreads();
  if (tid < 16) {
    float s2 = 0.f;
#pragma unroll
    for (int w2 = 0; w2 < 8; w2++) s2 += LV[w2][tid];
    LI[tid] = 1.0f / s2;
  }
  __syncthreads();

  // ctx partials (scaled) into LDS
  {
    float sc = LI[lq];
#pragma unroll
    for (int af = 0; af < 4; af++)
#pragma unroll
      for (int jj = 0; jj < 4; jj++)
        atomicAdd(&CT[lq][af * 16 + g * 4 + jj], acc[af][jj] * sc);
  }

  // attn store: 32 threads/row; per instr = 2 rows x 512 B contiguous NT
  {
    int r = tid >> 5, sl = tid & 31;
    float li = LI[r];
    int rs = (r & 7) << 4;
    const char* Pbase = (const char*)Pl + r * 512;
    float* arow = attn + ((size_t)bh * 2048 + rowbase + r) * 2048;
#pragma unroll
    for (int i = 0; i < 16; i++) {
      int col = i * 128 + sl * 4;
      int w2 = col >> 8;
      int lb = (col & 255) * 2;
      f16x4 pv = *(const f16x4*)(Pbase + w2 * 8192 + (lb ^ rs));
      f32x4 o = {(float)pv[0] * li, (float)pv[1] * li,
                 (float)pv[2] * li, (float)pv[3] * li};
      __builtin_nontemporal_store(o, (f32x4*)(arow + col));
    }
  }
  __syncthreads();

  // ctx store (16 rows x 64 dh f16)
  if (tid < 256) {
    int q2 = tid >> 4, d0 = (tid & 15) * 4;
    float4 c = *(const float4*)&CT[q2][d0];
    int b = bh >> 4, h = bh & 15;
    f16* crow = ctx + ((size_t)b * 2048 + rowbase + q2) * 1024 + h * 64 + d0;
    f16x4 y;
    y[0] = (f16)c.x; y[1] = (f16)c.y; y[2] = (f16)c.z; y[3] = (f16)c.w;
    *(f16x4*)crow = y;
  }
}

// ---------------------------------------------------------------------------
extern "C" void kernel_launch(void* const* d_in, const int* in_sizes, int n_in,
                              void* d_out, int out_size, void* d_ws,
                              size_t ws_size, hipStream_t stream) {
  (void)in_sizes; (void)n_in; (void)out_size; (void)ws_size;
  const float* q   = (const float*)d_in[0];
  const float* k   = (const float*)d_in[1];
  const float* v   = (const float*)d_in[2];
  const float* wq  = (const float*)d_in[3];
  const float* wk  = (const float*)d_in[4];
  const float* wv  = (const float*)d_in[5];
  const float* wfc = (const float*)d_in[6];
  const float* bfc = (const float*)d_in[7];

  f16* ws = (f16*)d_ws;
  f16* qf   = ws;                     // also base for k,v (stride 4194304)
  f16* wqf  = ws + 12582912;          // base for wq,wk,wv (stride 1048576)
  f16* wfcf = ws + 15728640;
  f16* qhp  = ws + 16777216;          // base for qh,kh,vt (stride 4194304)
  f16* khp  = ws + 20971520;
  f16* vtp  = ws + 25165824;
  f16* ctxp = ws + 29360128;          // [B,S,D]

  float* outp  = (float*)d_out;
  float* attnp = outp + 4194304;

  cast_all<<<16384, 256, 0, stream>>>(q, k, v, wq, wk, wv, wfc, ws);
  gemm_bt<4, 128><<<dim3(24, 32), 256, 0, stream>>>(qf, wqf, nullptr, qhp);
  attn_one<<<4096, 512, 0, stream>>>(qhp, khp, vtp, attnp, ctxp);
  gemm_bt<3, 64><<<dim3(16, 32), 256, 0, stream>>>(ctxp, wfcf, bfc, outp);
}